// Round 6
// baseline (478.015 us; speedup 1.0000x reference)
//
#include <hip/hip_runtime.h>

#define NN   100000
#define NE   1600000
#define DIM  128
#define NBKT 391                  // ceil(NN/256) buckets of 256 nodes
#define EPB  16384                // edges per binning block
#define NBLK 98                   // ceil(NE/EPB)
#define NTILES (NN / 16)          // 6250 node-tiles of 16 rows

typedef short          s16x8 __attribute__((ext_vector_type(8)));
typedef unsigned short u16x8 __attribute__((ext_vector_type(8)));
typedef float          f32x4 __attribute__((ext_vector_type(4)));

__device__ __forceinline__ unsigned short f2b(float f) {
    unsigned u = __float_as_uint(f);
    unsigned r = ((u >> 16) & 1u) + 0x7FFFu;   // RNE
    return (unsigned short)((u + r) >> 16);
}
__device__ __forceinline__ float b2f(unsigned short h) {
    return __uint_as_float(((unsigned)h) << 16);
}

// ---- fp32 -> bf16 feature cast (x table) ----
__global__ void k_cast_x(const float* __restrict__ x, unsigned short* __restrict__ xb) {
    int i = blockIdx.x * blockDim.x + threadIdx.x;     // over NN*DIM/4
    const float4* xp = (const float4*)x;
    float4 v = xp[i];
    ushort4 o;
    o.x = f2b(v.x); o.y = f2b(v.y); o.z = f2b(v.z); o.w = f2b(v.w);
    ((ushort4*)xb)[i] = o;
}

// ---- phase 1: per-block bucket histogram -> hist[k*NBLK + b] (bucket-major) ----
__global__ void k_hist2(const int* __restrict__ dst, int* __restrict__ hist) {
    __shared__ int lh[NBKT];
    int t = threadIdx.x, b = blockIdx.x;
    for (int j = t; j < NBKT; j += 256) lh[j] = 0;
    __syncthreads();
    int base = b * EPB;
    int end = base + EPB; if (end > NE) end = NE;
    for (int i = base + t; i < end; i += 256) atomicAdd(&lh[dst[i] >> 8], 1);
    __syncthreads();
    for (int j = t; j < NBKT; j += 256) hist[j * NBLK + b] = lh[j];
}

// ---- phase 2a: per-bucket row scan (exclusive over the 98 block counts) ----
__global__ void k_scanrow(int* __restrict__ hist, int* __restrict__ row_total) {
    __shared__ int sh[128];
    int k = blockIdx.x, t = threadIdx.x;
    int v = (t < NBLK) ? hist[k * NBLK + t] : 0;
    sh[t] = v;
    __syncthreads();
    for (int off = 1; off < 128; off <<= 1) {
        int a = (t >= off) ? sh[t - off] : 0;
        __syncthreads();
        sh[t] += a;
        __syncthreads();
    }
    if (t < NBLK) hist[k * NBLK + t] = sh[t] - v;   // exclusive within row
    if (t == 127) row_total[k] = sh[127];
}

// ---- phase 2b: exclusive scan of 391 bucket totals, single block ----
__global__ void k_scanbkt(const int* __restrict__ row_total, int* __restrict__ bbase) {
    __shared__ int sh[512];
    int t = threadIdx.x;
    int v = (t < NBKT) ? row_total[t] : 0;
    sh[t] = v;
    __syncthreads();
    for (int off = 1; off < 512; off <<= 1) {
        int a = (t >= off) ? sh[t - off] : 0;
        __syncthreads();
        sh[t] += a;
        __syncthreads();
    }
    if (t < NBKT) bbase[t] = sh[t] - v;
    if (t == NBKT) bbase[NBKT] = NE;
}

// ---- phase 3: bin edges deterministically: word = (src<<8)|(dst&255) ----
__global__ void k_bin2(const int* __restrict__ src, const int* __restrict__ dst,
                       const int* __restrict__ hist, const int* __restrict__ bbase,
                       int* __restrict__ binned) {
    __shared__ int s_base[NBKT];
    __shared__ int s_cnt[NBKT];
    int t = threadIdx.x, b = blockIdx.x;
    for (int j = t; j < NBKT; j += 256) {
        s_base[j] = bbase[j] + hist[j * NBLK + b];
        s_cnt[j] = 0;
    }
    __syncthreads();
    int base = b * EPB;
    int end = base + EPB; if (end > NE) end = NE;
    for (int i = base + t; i < end; i += 256) {
        int d = dst[i];
        int k = d >> 8;
        int w = (src[i] << 8) | (d & 255);
        int lpos = atomicAdd(&s_cnt[k], 1);
        binned[s_base[k] + lpos] = w;
    }
}

// ---- per-bucket CSR build: LDS degree hist + scan + staged coalesced write ----
__global__ void k_build(const int* __restrict__ binned,
                        const int* __restrict__ bucket_base,
                        int* __restrict__ csr,
                        int* __restrict__ row_start, int* __restrict__ deg,
                        float* __restrict__ deg_inv) {
    __shared__ int s_deg[256], s_scan[256], s_cur[256];
    __shared__ int stage[8192];
    int b = blockIdx.x, t = threadIdx.x;
    int base = bucket_base[b], end = bucket_base[b + 1];
    int cnt = end - base;
    s_deg[t] = 0;
    __syncthreads();
    for (int i = t; i < cnt; i += 256)
        atomicAdd(&s_deg[binned[base + i] & 255], 1);
    __syncthreads();
    s_scan[t] = s_deg[t];
    __syncthreads();
    for (int off = 1; off < 256; off <<= 1) {
        int a = (t >= off) ? s_scan[t - off] : 0;
        __syncthreads();
        s_scan[t] += a;
        __syncthreads();
    }
    int excl = s_scan[t] - s_deg[t];
    s_cur[t] = excl;
    int node = b * 256 + t;
    if (node < NN) {
        int d = s_deg[t];
        row_start[node] = base + excl;
        deg[node]       = d;
        deg_inv[node]   = (d > 0) ? 1.0f / (float)d : 0.0f;
    }
    __syncthreads();
    for (int i = t; i < cnt; i += 256) {
        int w = binned[base + i];           // L2-hot second read
        int pos = atomicAdd(&s_cur[w & 255], 1);
        int s = w >> 8;
        if (pos < 8192) stage[pos] = s;
        else            csr[base + pos] = s;   // overflow fallback (not expected)
    }
    __syncthreads();
    int m = cnt < 8192 ? cnt : 8192;
    for (int i = t; i < m; i += 256) csr[base + i] = stage[i];
}

// ---- weight cast: Wt[n][k] = bf16( k<128 ? Wl[k][n] : Wr[k-128][n] ), 3 layers ----
__global__ void k_castw(const float* __restrict__ W1l, const float* __restrict__ W1r,
                        const float* __restrict__ W2l, const float* __restrict__ W2r,
                        const float* __restrict__ W3l, const float* __restrict__ W3r,
                        unsigned short* __restrict__ Wt1, unsigned short* __restrict__ Wt2,
                        unsigned short* __restrict__ Wt3) {
    int i = blockIdx.x * blockDim.x + threadIdx.x;   // 3 * 128 * 256
    int L = i >> 15;
    int rem = i & 32767;
    int n = rem >> 8;
    int k = rem & 255;
    const float* Wl = (L == 0) ? W1l : (L == 1) ? W2l : W3l;
    const float* Wr = (L == 0) ? W1r : (L == 1) ? W2r : W3r;
    unsigned short* Wt = (L == 0) ? Wt1 : (L == 1) ? Wt2 : Wt3;
    float v = (k < 128) ? Wl[k * 128 + n] : Wr[(k - 128) * 128 + n];
    Wt[n * 256 + k] = f2b(v);
}

// ---- mean aggregation: one wave per node; 4 neighbor slots x 16 col-chunks ----
// 4 independent load+accumulate chains per lane (stride-16 j loop) for MLP.
__global__ void k_gather(const unsigned short* __restrict__ feat,
                         const int* __restrict__ row_start, const int* __restrict__ deg,
                         const float* __restrict__ deg_inv, const int* __restrict__ csr,
                         unsigned short* __restrict__ mean) {
    int lane = threadIdx.x & 63;
    int wv   = threadIdx.x >> 6;
    int n    = blockIdx.x * 4 + wv;        // NN % 4 == 0, grid exact
    int q = lane >> 4, c = lane & 15;      // q: neighbor slot, c: 16B column chunk
    int base = row_start[n];
    int d    = deg[n];
    float acc0[8], acc1[8], acc2[8], acc3[8];
#pragma unroll
    for (int t = 0; t < 8; t++) { acc0[t] = 0.f; acc1[t] = 0.f; acc2[t] = 0.f; acc3[t] = 0.f; }
    const u16x8* fp = (const u16x8*)feat;
    int j = q;
    for (; j + 12 < d; j += 16) {
        int s0 = csr[base + j];
        int s1 = csr[base + j + 4];
        int s2 = csr[base + j + 8];
        int s3 = csr[base + j + 12];
        u16x8 v0 = fp[s0 * 16 + c];
        u16x8 v1 = fp[s1 * 16 + c];
        u16x8 v2 = fp[s2 * 16 + c];
        u16x8 v3 = fp[s3 * 16 + c];
#pragma unroll
        for (int t = 0; t < 8; t++) {
            acc0[t] += b2f(v0[t]); acc1[t] += b2f(v1[t]);
            acc2[t] += b2f(v2[t]); acc3[t] += b2f(v3[t]);
        }
    }
    for (; j + 4 < d; j += 8) {
        int s0 = csr[base + j];
        int s1 = csr[base + j + 4];
        u16x8 v0 = fp[s0 * 16 + c];
        u16x8 v1 = fp[s1 * 16 + c];
#pragma unroll
        for (int t = 0; t < 8; t++) { acc0[t] += b2f(v0[t]); acc1[t] += b2f(v1[t]); }
    }
    if (j < d) {
        int s0 = csr[base + j];
        u16x8 v0 = fp[s0 * 16 + c];
#pragma unroll
        for (int t = 0; t < 8; t++) acc0[t] += b2f(v0[t]);
    }
#pragma unroll
    for (int t = 0; t < 8; t++) acc0[t] += (acc1[t] + acc2[t]) + acc3[t];
#pragma unroll
    for (int t = 0; t < 8; t++) {
        acc0[t] += __shfl_xor(acc0[t], 16, 64);
        acc0[t] += __shfl_xor(acc0[t], 32, 64);
    }
    if (q == 0) {
        float s = deg_inv[n];
        u16x8 o;
#pragma unroll
        for (int t = 0; t < 8; t++) o[t] = f2b(acc0[t] * s);
        ((u16x8*)mean)[n * 16 + c] = o;
    }
}

// ---- fused linear v3: LDS weights as MFMA *A*-operand; D[outdim][node] ----
// acc = mfma(W_frag, X_frag): col(lane&15)=node, row(quad*4+r)=outdim ->
// each lane holds 4 consecutive outdims for one node -> packed 8B/16B stores.
// MODE 0: relu, bf16 output; MODE 1: no act, fp32 output
template <int MODE>
__global__ void __launch_bounds__(512)
k_lin(const unsigned short* __restrict__ meanb,
      const unsigned short* __restrict__ hb,
      const unsigned short* __restrict__ Wt,
      const float* __restrict__ bias, void* __restrict__ out) {
    __shared__ s16x8 sW[4096];             // 64 KB
    int t = threadIdx.x;
    const s16x8* wp = (const s16x8*)Wt;
    // stage in fragment order: chunk ci -> frag (ci>>6), lane (ci&63)
    // A-frag for tile (mt,kt): m = mt*16 + (lane&15), k-chunk = kt*4 + (lane>>4)
#pragma unroll
    for (int it = 0; it < 8; it++) {
        int ci = it * 512 + t;
        int frag = ci >> 6, ln = ci & 63;
        int mt = frag >> 3, kt = frag & 7;
        int m = mt * 16 + (ln & 15);
        int kc = kt * 4 + (ln >> 4);
        sW[ci] = wp[m * 32 + kc];
    }
    __syncthreads();

    int lane = t & 63;
    int wv   = t >> 6;
    int tile = blockIdx.x * 8 + wv;        // node tile (16 nodes)
    if (tile >= NTILES) return;
    int n0 = tile * 16;
    int q = lane >> 4, c = lane & 15;
    const s16x8* mp = (const s16x8*)meanb;
    const s16x8* hp = (const s16x8*)hb;
    int row = n0 + c;                      // B: n(node) = lane&15, k-chunk = quad*8
    s16x8 B[8];
#pragma unroll
    for (int kt = 0; kt < 4; kt++) B[kt] = mp[row * 16 + kt * 4 + q];
#pragma unroll
    for (int kt = 0; kt < 4; kt++) B[4 + kt] = hp[row * 16 + kt * 4 + q];
    const f32x4* bp = (const f32x4*)bias;
#pragma unroll
    for (int mt = 0; mt < 8; mt++) {
        f32x4 acc = {0.f, 0.f, 0.f, 0.f};
#pragma unroll
        for (int kt = 0; kt < 8; kt++)
            acc = __builtin_amdgcn_mfma_f32_16x16x32_bf16(sW[(mt * 8 + kt) * 64 + lane],
                                                          B[kt], acc, 0, 0, 0);
        f32x4 bv = bp[mt * 4 + q];         // outdims mt*16+q*4 .. +3 (wave-uniform/quad)
        int node = n0 + c;
        if (MODE == 0) {
            ushort4 o;
            float v0 = acc[0] + bv[0]; if (v0 < 0.f) v0 = 0.f;
            float v1 = acc[1] + bv[1]; if (v1 < 0.f) v1 = 0.f;
            float v2 = acc[2] + bv[2]; if (v2 < 0.f) v2 = 0.f;
            float v3 = acc[3] + bv[3]; if (v3 < 0.f) v3 = 0.f;
            o.x = f2b(v0); o.y = f2b(v1); o.z = f2b(v2); o.w = f2b(v3);
            ((ushort4*)out)[node * 32 + mt * 4 + q] = o;
        } else {
            f32x4 v;
#pragma unroll
            for (int r = 0; r < 4; r++) v[r] = acc[r] + bv[r];
            ((f32x4*)out)[node * 32 + mt * 4 + q] = v;
        }
    }
}

extern "C" void kernel_launch(void* const* d_in, const int* in_sizes, int n_in,
                              void* d_out, int out_size, void* d_ws, size_t ws_size,
                              hipStream_t stream) {
    const float* x   = (const float*)d_in[1];
    const int*   ei  = (const int*)d_in[2];
    const int*   src = ei;
    const int*   dst = ei + NE;
    const float* W1l = (const float*)d_in[3];
    const float* W1r = (const float*)d_in[4];
    const float* b1  = (const float*)d_in[5];
    const float* W2l = (const float*)d_in[6];
    const float* W2r = (const float*)d_in[7];
    const float* b2  = (const float*)d_in[8];
    const float* W3l = (const float*)d_in[9];
    const float* W3r = (const float*)d_in[10];
    const float* b3  = (const float*)d_in[11];

    // workspace carve (all 256B aligned)
    char* w = (char*)d_ws;
    auto carve = [&](size_t bytes) {
        void* p = (void*)w;
        w += (bytes + 255) & ~(size_t)255;
        return p;
    };
    int*   row_start = (int*)carve(NN * 4);
    int*   deg       = (int*)carve(NN * 4);
    float* deg_inv   = (float*)carve(NN * 4);
    int*   hist      = (int*)carve((size_t)NBKT * NBLK * 4);
    int*   row_total = (int*)carve(NBKT * 4);
    int*   bbase     = (int*)carve((NBKT + 1) * 4);
    int*   csr       = (int*)carve((size_t)NE * 4);
    unsigned short* Wt1 = (unsigned short*)carve(128 * 256 * 2);
    unsigned short* Wt2 = (unsigned short*)carve(128 * 256 * 2);
    unsigned short* Wt3 = (unsigned short*)carve(128 * 256 * 2);
    unsigned short* xb    = (unsigned short*)carve((size_t)NN * DIM * 2);
    unsigned short* meanb = (unsigned short*)carve((size_t)NN * DIM * 2);
    unsigned short* h1b   = (unsigned short*)carve((size_t)NN * DIM * 2);
    unsigned short* h2b   = xb;          // x dead after layer-2 B-load
    int*   binned    = (int*)meanb;      // binned (6.4 MB) dead before first k_gather

    k_cast_x<<<NN * DIM / 4 / 256, 256, 0, stream>>>(x, xb);
    k_hist2<<<NBLK, 256, 0, stream>>>(dst, hist);
    k_scanrow<<<NBKT, 128, 0, stream>>>(hist, row_total);
    k_scanbkt<<<1, 512, 0, stream>>>(row_total, bbase);
    k_bin2<<<NBLK, 256, 0, stream>>>(src, dst, hist, bbase, binned);
    k_build<<<NBKT, 256, 0, stream>>>(binned, bbase, csr, row_start, deg, deg_inv);
    k_castw<<<3 * 128 * 256 / 256, 256, 0, stream>>>(W1l, W1r, W2l, W2r, W3l, W3r,
                                                     Wt1, Wt2, Wt3);

    const int GB = NN / 4;                  // gather blocks (4 waves = 4 nodes each)
    const int LB = (NTILES + 7) / 8;        // k_lin blocks (8 waves = 8 tiles each)

    // layer 1: mean over xb -> h1 = relu(lin)
    k_gather<<<GB, 256, 0, stream>>>(xb, row_start, deg, deg_inv, csr, meanb);
    k_lin<0><<<LB, 512, 0, stream>>>(meanb, xb, Wt1, b1, (void*)h1b);
    // layer 2: mean over h1 -> h2 = relu(lin)
    k_gather<<<GB, 256, 0, stream>>>(h1b, row_start, deg, deg_inv, csr, meanb);
    k_lin<0><<<LB, 512, 0, stream>>>(meanb, h1b, Wt2, b2, (void*)h2b);
    // layer 3: mean over h2 -> dx_dt (fp32, no activation)
    k_gather<<<GB, 256, 0, stream>>>(h2b, row_start, deg, deg_inv, csr, meanb);
    k_lin<1><<<LB, 512, 0, stream>>>(meanb, h2b, Wt3, b3, d_out);
}

// Round 7
// 451.607 us; speedup vs baseline: 1.0585x; 1.0585x over previous
//
#include <hip/hip_runtime.h>

#define NN   100000
#define NE   1600000
#define DIM  128
#define NBKT 391                  // ceil(NN/256) buckets of 256 nodes
#define EPB  16384                // edges per binning block
#define NBLK 98                   // ceil(NE/EPB)
#define NTILES (NN / 16)          // 6250 node-tiles of 16 rows
#define CASTB 12500               // cast_x blocks (NN*DIM/4/256)
#define CWB   384                 // castw blocks (3*128*256/256)

typedef short          s16x8 __attribute__((ext_vector_type(8)));
typedef unsigned short u16x8 __attribute__((ext_vector_type(8)));
typedef float          f32x4 __attribute__((ext_vector_type(4)));

__device__ __forceinline__ unsigned short f2b(float f) {
    unsigned u = __float_as_uint(f);
    unsigned r = ((u >> 16) & 1u) + 0x7FFFu;   // RNE
    return (unsigned short)((u + r) >> 16);
}
__device__ __forceinline__ float b2f(unsigned short h) {
    return __uint_as_float(((unsigned)h) << 16);
}

// ---- fused prep: [0,NBLK) hist | [NBLK,NBLK+CASTB) cast_x | rest castw ----
__global__ void k_prep(const float* __restrict__ x, unsigned short* __restrict__ xb,
                       const int* __restrict__ dst, int* __restrict__ hist,
                       const float* __restrict__ W1l, const float* __restrict__ W1r,
                       const float* __restrict__ W2l, const float* __restrict__ W2r,
                       const float* __restrict__ W3l, const float* __restrict__ W3r,
                       unsigned short* __restrict__ Wt1, unsigned short* __restrict__ Wt2,
                       unsigned short* __restrict__ Wt3) {
    __shared__ int lh[NBKT];
    int t = threadIdx.x, b = blockIdx.x;
    if (b < NBLK) {
        // bucket histogram -> hist[k*NBLK + b] (bucket-major)
        for (int j = t; j < NBKT; j += 256) lh[j] = 0;
        __syncthreads();
        int base = b * EPB;
        int end = base + EPB; if (end > NE) end = NE;
        for (int i = base + t; i < end; i += 256) atomicAdd(&lh[dst[i] >> 8], 1);
        __syncthreads();
        for (int j = t; j < NBKT; j += 256) hist[j * NBLK + b] = lh[j];
    } else if (b < NBLK + CASTB) {
        // fp32 -> bf16 feature cast
        int i = (b - NBLK) * 256 + t;
        float4 v = ((const float4*)x)[i];
        ushort4 o;
        o.x = f2b(v.x); o.y = f2b(v.y); o.z = f2b(v.z); o.w = f2b(v.w);
        ((ushort4*)xb)[i] = o;
    } else {
        // weight cast: Wt[n][k] = bf16( k<128 ? Wl[k][n] : Wr[k-128][n] )
        int i = (b - NBLK - CASTB) * 256 + t;   // 3 * 128 * 256
        int L = i >> 15;
        int rem = i & 32767;
        int n = rem >> 8;
        int k = rem & 255;
        const float* Wl = (L == 0) ? W1l : (L == 1) ? W2l : W3l;
        const float* Wr = (L == 0) ? W1r : (L == 1) ? W2r : W3r;
        unsigned short* Wt = (L == 0) ? Wt1 : (L == 1) ? Wt2 : Wt3;
        float v = (k < 128) ? Wl[k * 128 + n] : Wr[(k - 128) * 128 + n];
        Wt[n * 256 + k] = f2b(v);
    }
}

// ---- phase 2a: per-bucket row scan (exclusive over the 98 block counts) ----
__global__ void k_scanrow(int* __restrict__ hist, int* __restrict__ row_total) {
    __shared__ int sh[128];
    int k = blockIdx.x, t = threadIdx.x;
    int v = (t < NBLK) ? hist[k * NBLK + t] : 0;
    sh[t] = v;
    __syncthreads();
    for (int off = 1; off < 128; off <<= 1) {
        int a = (t >= off) ? sh[t - off] : 0;
        __syncthreads();
        sh[t] += a;
        __syncthreads();
    }
    if (t < NBLK) hist[k * NBLK + t] = sh[t] - v;   // exclusive within row
    if (t == 127) row_total[k] = sh[127];
}

// ---- phase 2b: exclusive scan of 391 bucket totals, single block ----
__global__ void k_scanbkt(const int* __restrict__ row_total, int* __restrict__ bbase) {
    __shared__ int sh[512];
    int t = threadIdx.x;
    int v = (t < NBKT) ? row_total[t] : 0;
    sh[t] = v;
    __syncthreads();
    for (int off = 1; off < 512; off <<= 1) {
        int a = (t >= off) ? sh[t - off] : 0;
        __syncthreads();
        sh[t] += a;
        __syncthreads();
    }
    if (t < NBKT) bbase[t] = sh[t] - v;
    if (t == NBKT) bbase[NBKT] = NE;
}

// ---- phase 3: bin edges deterministically: word = (src<<8)|(dst&255) ----
__global__ void k_bin2(const int* __restrict__ src, const int* __restrict__ dst,
                       const int* __restrict__ hist, const int* __restrict__ bbase,
                       int* __restrict__ binned) {
    __shared__ int s_base[NBKT];
    __shared__ int s_cnt[NBKT];
    int t = threadIdx.x, b = blockIdx.x;
    for (int j = t; j < NBKT; j += 256) {
        s_base[j] = bbase[j] + hist[j * NBLK + b];
        s_cnt[j] = 0;
    }
    __syncthreads();
    int base = b * EPB;
    int end = base + EPB; if (end > NE) end = NE;
    for (int i = base + t; i < end; i += 256) {
        int d = dst[i];
        int k = d >> 8;
        int w = (src[i] << 8) | (d & 255);
        int lpos = atomicAdd(&s_cnt[k], 1);
        binned[s_base[k] + lpos] = w;
    }
}

// ---- per-bucket CSR build: LDS degree hist + scan + staged coalesced write ----
__global__ void k_build(const int* __restrict__ binned,
                        const int* __restrict__ bucket_base,
                        int* __restrict__ csr,
                        int* __restrict__ row_start, int* __restrict__ deg,
                        float* __restrict__ deg_inv) {
    __shared__ int s_deg[256], s_scan[256], s_cur[256];
    __shared__ int stage[8192];
    int b = blockIdx.x, t = threadIdx.x;
    int base = bucket_base[b], end = bucket_base[b + 1];
    int cnt = end - base;
    s_deg[t] = 0;
    __syncthreads();
    for (int i = t; i < cnt; i += 256)
        atomicAdd(&s_deg[binned[base + i] & 255], 1);
    __syncthreads();
    s_scan[t] = s_deg[t];
    __syncthreads();
    for (int off = 1; off < 256; off <<= 1) {
        int a = (t >= off) ? s_scan[t - off] : 0;
        __syncthreads();
        s_scan[t] += a;
        __syncthreads();
    }
    int excl = s_scan[t] - s_deg[t];
    s_cur[t] = excl;
    int node = b * 256 + t;
    if (node < NN) {
        int d = s_deg[t];
        row_start[node] = base + excl;
        deg[node]       = d;
        deg_inv[node]   = (d > 0) ? 1.0f / (float)d : 0.0f;
    }
    __syncthreads();
    for (int i = t; i < cnt; i += 256) {
        int w = binned[base + i];           // L2-hot second read
        int pos = atomicAdd(&s_cur[w & 255], 1);
        int s = w >> 8;
        if (pos < 8192) stage[pos] = s;
        else            csr[base + pos] = s;   // overflow fallback (not expected)
    }
    __syncthreads();
    int m = cnt < 8192 ? cnt : 8192;
    for (int i = t; i < m; i += 256) csr[base + i] = stage[i];
}

// ---- mean aggregation: one wave per node; 4 neighbor slots x 16 col-chunks ----
// 2 independent load+accumulate chains per lane (R5-proven: more chains regress
// — random-access request path saturates ~6.7 TB/s; extra VGPRs cost occupancy).
__global__ void k_gather(const unsigned short* __restrict__ feat,
                         const int* __restrict__ row_start, const int* __restrict__ deg,
                         const float* __restrict__ deg_inv, const int* __restrict__ csr,
                         unsigned short* __restrict__ mean) {
    int lane = threadIdx.x & 63;
    int wv   = threadIdx.x >> 6;
    int n    = blockIdx.x * 4 + wv;        // NN % 4 == 0, grid exact
    int q = lane >> 4, c = lane & 15;      // q: neighbor slot, c: 16B column chunk
    int base = row_start[n];
    int d    = deg[n];
    float acc0[8], acc1[8];
#pragma unroll
    for (int t = 0; t < 8; t++) { acc0[t] = 0.0f; acc1[t] = 0.0f; }
    const u16x8* fp = (const u16x8*)feat;
    int j = q;
    for (; j + 4 < d; j += 8) {
        int s0 = csr[base + j];
        int s1 = csr[base + j + 4];
        u16x8 v0 = fp[s0 * 16 + c];
        u16x8 v1 = fp[s1 * 16 + c];
#pragma unroll
        for (int t = 0; t < 8; t++) { acc0[t] += b2f(v0[t]); acc1[t] += b2f(v1[t]); }
    }
    if (j < d) {
        int s0 = csr[base + j];
        u16x8 v0 = fp[s0 * 16 + c];
#pragma unroll
        for (int t = 0; t < 8; t++) acc0[t] += b2f(v0[t]);
    }
#pragma unroll
    for (int t = 0; t < 8; t++) acc0[t] += acc1[t];
#pragma unroll
    for (int t = 0; t < 8; t++) {
        acc0[t] += __shfl_xor(acc0[t], 16, 64);
        acc0[t] += __shfl_xor(acc0[t], 32, 64);
    }
    if (q == 0) {
        float s = deg_inv[n];
        u16x8 o;
#pragma unroll
        for (int t = 0; t < 8; t++) o[t] = f2b(acc0[t] * s);
        ((u16x8*)mean)[n * 16 + c] = o;
    }
}

// ---- fused linear v3: LDS weights as MFMA *A*-operand; D[outdim][node] ----
// acc = mfma(W_frag, X_frag): col(lane&15)=node, row(quad*4+r)=outdim ->
// each lane holds 4 consecutive outdims for one node -> packed 8B/16B stores.
// MODE 0: relu, bf16 output; MODE 1: no act, fp32 output
template <int MODE>
__global__ void __launch_bounds__(512)
k_lin(const unsigned short* __restrict__ meanb,
      const unsigned short* __restrict__ hb,
      const unsigned short* __restrict__ Wt,
      const float* __restrict__ bias, void* __restrict__ out) {
    __shared__ s16x8 sW[4096];             // 64 KB
    int t = threadIdx.x;
    const s16x8* wp = (const s16x8*)Wt;
    // stage in fragment order: chunk ci -> frag (ci>>6), lane (ci&63)
    // A-frag for tile (mt,kt): m = mt*16 + (lane&15), k-chunk = kt*4 + (lane>>4)
#pragma unroll
    for (int it = 0; it < 8; it++) {
        int ci = it * 512 + t;
        int frag = ci >> 6, ln = ci & 63;
        int mt = frag >> 3, kt = frag & 7;
        int m = mt * 16 + (ln & 15);
        int kc = kt * 4 + (ln >> 4);
        sW[ci] = wp[m * 32 + kc];
    }
    __syncthreads();

    int lane = t & 63;
    int wv   = t >> 6;
    int tile = blockIdx.x * 8 + wv;        // node tile (16 nodes)
    if (tile >= NTILES) return;
    int n0 = tile * 16;
    int q = lane >> 4, c = lane & 15;
    const s16x8* mp = (const s16x8*)meanb;
    const s16x8* hp = (const s16x8*)hb;
    int row = n0 + c;                      // B: n(node) = lane&15, k-chunk = quad*8
    s16x8 B[8];
#pragma unroll
    for (int kt = 0; kt < 4; kt++) B[kt] = mp[row * 16 + kt * 4 + q];
#pragma unroll
    for (int kt = 0; kt < 4; kt++) B[4 + kt] = hp[row * 16 + kt * 4 + q];
    const f32x4* bp = (const f32x4*)bias;
#pragma unroll
    for (int mt = 0; mt < 8; mt++) {
        f32x4 acc = {0.f, 0.f, 0.f, 0.f};
#pragma unroll
        for (int kt = 0; kt < 8; kt++)
            acc = __builtin_amdgcn_mfma_f32_16x16x32_bf16(sW[(mt * 8 + kt) * 64 + lane],
                                                          B[kt], acc, 0, 0, 0);
        f32x4 bv = bp[mt * 4 + q];         // outdims mt*16+q*4 .. +3
        int node = n0 + c;
        if (MODE == 0) {
            ushort4 o;
            float v0 = acc[0] + bv[0]; if (v0 < 0.f) v0 = 0.f;
            float v1 = acc[1] + bv[1]; if (v1 < 0.f) v1 = 0.f;
            float v2 = acc[2] + bv[2]; if (v2 < 0.f) v2 = 0.f;
            float v3 = acc[3] + bv[3]; if (v3 < 0.f) v3 = 0.f;
            o.x = f2b(v0); o.y = f2b(v1); o.z = f2b(v2); o.w = f2b(v3);
            ((ushort4*)out)[node * 32 + mt * 4 + q] = o;
        } else {
            f32x4 v;
#pragma unroll
            for (int r = 0; r < 4; r++) v[r] = acc[r] + bv[r];
            ((f32x4*)out)[node * 32 + mt * 4 + q] = v;
        }
    }
}

extern "C" void kernel_launch(void* const* d_in, const int* in_sizes, int n_in,
                              void* d_out, int out_size, void* d_ws, size_t ws_size,
                              hipStream_t stream) {
    const float* x   = (const float*)d_in[1];
    const int*   ei  = (const int*)d_in[2];
    const int*   src = ei;
    const int*   dst = ei + NE;
    const float* W1l = (const float*)d_in[3];
    const float* W1r = (const float*)d_in[4];
    const float* b1  = (const float*)d_in[5];
    const float* W2l = (const float*)d_in[6];
    const float* W2r = (const float*)d_in[7];
    const float* b2  = (const float*)d_in[8];
    const float* W3l = (const float*)d_in[9];
    const float* W3r = (const float*)d_in[10];
    const float* b3  = (const float*)d_in[11];

    // workspace carve (all 256B aligned)
    char* w = (char*)d_ws;
    auto carve = [&](size_t bytes) {
        void* p = (void*)w;
        w += (bytes + 255) & ~(size_t)255;
        return p;
    };
    int*   row_start = (int*)carve(NN * 4);
    int*   deg       = (int*)carve(NN * 4);
    float* deg_inv   = (float*)carve(NN * 4);
    int*   hist      = (int*)carve((size_t)NBKT * NBLK * 4);
    int*   row_total = (int*)carve(NBKT * 4);
    int*   bbase     = (int*)carve((NBKT + 1) * 4);
    int*   csr       = (int*)carve((size_t)NE * 4);
    unsigned short* Wt1 = (unsigned short*)carve(128 * 256 * 2);
    unsigned short* Wt2 = (unsigned short*)carve(128 * 256 * 2);
    unsigned short* Wt3 = (unsigned short*)carve(128 * 256 * 2);
    unsigned short* xb    = (unsigned short*)carve((size_t)NN * DIM * 2);
    unsigned short* meanb = (unsigned short*)carve((size_t)NN * DIM * 2);
    unsigned short* h1b   = (unsigned short*)carve((size_t)NN * DIM * 2);
    unsigned short* h2b   = xb;          // x dead after layer-2 B-load
    int*   binned    = (int*)meanb;      // binned (6.4 MB) dead before first k_gather

    k_prep<<<NBLK + CASTB + CWB, 256, 0, stream>>>(x, xb, dst, hist,
                                                   W1l, W1r, W2l, W2r, W3l, W3r,
                                                   Wt1, Wt2, Wt3);
    k_scanrow<<<NBKT, 128, 0, stream>>>(hist, row_total);
    k_scanbkt<<<1, 512, 0, stream>>>(row_total, bbase);
    k_bin2<<<NBLK, 256, 0, stream>>>(src, dst, hist, bbase, binned);
    k_build<<<NBKT, 256, 0, stream>>>(binned, bbase, csr, row_start, deg, deg_inv);

    const int GB = NN / 4;                  // gather blocks (4 waves = 4 nodes each)
    const int LB = (NTILES + 7) / 8;        // k_lin blocks (8 waves = 8 tiles each)

    // layer 1: mean over xb -> h1 = relu(lin)
    k_gather<<<GB, 256, 0, stream>>>(xb, row_start, deg, deg_inv, csr, meanb);
    k_lin<0><<<LB, 512, 0, stream>>>(meanb, xb, Wt1, b1, (void*)h1b);
    // layer 2: mean over h1 -> h2 = relu(lin)
    k_gather<<<GB, 256, 0, stream>>>(h1b, row_start, deg, deg_inv, csr, meanb);
    k_lin<0><<<LB, 512, 0, stream>>>(meanb, h1b, Wt2, b2, (void*)h2b);
    // layer 3: mean over h2 -> dx_dt (fp32, no activation)
    k_gather<<<GB, 256, 0, stream>>>(h2b, row_start, deg, deg_inv, csr, meanb);
    k_lin<1><<<LB, 512, 0, stream>>>(meanb, h2b, Wt3, b3, d_out);
}